// Round 6
// baseline (624.294 us; speedup 1.0000x reference)
//
#include <hip/hip_runtime.h>

#define T_STEPS 512
#define HID 128

typedef float vf4 __attribute__((ext_vector_type(4)));

// 1024 blocks (one batch row each) x 256 threads (4 waves).
// Thread (j = tid&127, half = tid>>7) computes the k-half [64*half, 64*half+64)
// of output j's dot product. Only 64 weights/thread -> register pressure ~90,
// below every RA eviction threshold (r3-r5 showed 128 weights/thread get
// evicted to AGPR/remat and re-read every step, +~180 instr/step).
// Weights live in 16 named vf4 SSA values, asm-pinned as IN-OUT operands each
// iteration: an asm output cannot be rematerialized, so eviction is pointless.
// Broadcast of h via v_readlane from a per-wave register holding its k-half.
__global__ __launch_bounds__(256, 4)
void rnn_scan_kernel(const float* __restrict__ x,
                     const float* __restrict__ W_ih,
                     const float* __restrict__ W_hh,
                     const float* __restrict__ b_ih,
                     const float* __restrict__ b_hh,
                     const float* __restrict__ W_out,
                     const float* __restrict__ b_out,
                     float* __restrict__ y)
{
    const int tid  = threadIdx.x;
    const int j    = tid & 127;     // output index
    const int half = tid >> 7;      // which k-half this thread accumulates
    const int lane = tid & 63;
    const int wid  = tid >> 6;      // wave id 0..3

    __shared__ float hbuf[2][HID];
    __shared__ float pbuf[HID];
    __shared__ float xs[T_STEPS];
    __shared__ float red[4];

    // --- 64 weights -> 16 named vf4 registers
    const float* wrow = W_hh + j * HID + half * 64;
    vf4 w00 = *(const vf4*)(wrow +  0);
    vf4 w01 = *(const vf4*)(wrow +  4);
    vf4 w02 = *(const vf4*)(wrow +  8);
    vf4 w03 = *(const vf4*)(wrow + 12);
    vf4 w04 = *(const vf4*)(wrow + 16);
    vf4 w05 = *(const vf4*)(wrow + 20);
    vf4 w06 = *(const vf4*)(wrow + 24);
    vf4 w07 = *(const vf4*)(wrow + 28);
    vf4 w08 = *(const vf4*)(wrow + 32);
    vf4 w09 = *(const vf4*)(wrow + 36);
    vf4 w10 = *(const vf4*)(wrow + 40);
    vf4 w11 = *(const vf4*)(wrow + 44);
    vf4 w12 = *(const vf4*)(wrow + 48);
    vf4 w13 = *(const vf4*)(wrow + 52);
    vf4 w14 = *(const vf4*)(wrow + 56);
    vf4 w15 = *(const vf4*)(wrow + 60);

    const float wih_j  = W_ih[j];
    const float bias_j = b_ih[j] + b_hh[j];

    // --- x for this sequence -> LDS (one coalesced pass)
    const float* xrow = x + (size_t)blockIdx.x * T_STEPS;   // x is [B, T, 1]
    xs[tid]       = xrow[tid];
    xs[tid + 256] = xrow[tid + 256];
    // (first __syncthreads below makes xs visible before first use)

    float hsrc = 0.0f;   // lane L holds h[half*64 + L]  (h0 = 0)
    float hA   = 0.0f;   // half-0 threads: h[j] after each step

#define RL(S, L) __int_as_float(__builtin_amdgcn_readlane((S), (L)))
#define DOT4(W, B)                                   \
    acc0 = fmaf(RL(hs, (B)+0), (W)[0], acc0);        \
    acc1 = fmaf(RL(hs, (B)+1), (W)[1], acc1);        \
    acc2 = fmaf(RL(hs, (B)+2), (W)[2], acc2);        \
    acc3 = fmaf(RL(hs, (B)+3), (W)[3], acc3);

    for (int t = 0; t < T_STEPS; ++t) {
        // Pin weights in ArchVGPRs at the top of every iteration.
        asm volatile("" : "+v"(w00), "+v"(w01), "+v"(w02), "+v"(w03),
                          "+v"(w04), "+v"(w05), "+v"(w06), "+v"(w07),
                          "+v"(w08), "+v"(w09), "+v"(w10), "+v"(w11),
                          "+v"(w12), "+v"(w13), "+v"(w14), "+v"(w15));

        const int hs = __float_as_int(hsrc);
        float acc0 = 0.0f, acc1 = 0.0f, acc2 = 0.0f, acc3 = 0.0f;
        DOT4(w00,  0) DOT4(w01,  4) DOT4(w02,  8) DOT4(w03, 12)
        DOT4(w04, 16) DOT4(w05, 20) DOT4(w06, 24) DOT4(w07, 28)
        DOT4(w08, 32) DOT4(w09, 36) DOT4(w10, 40) DOT4(w11, 44)
        DOT4(w12, 48) DOT4(w13, 52) DOT4(w14, 56) DOT4(w15, 60)
        const float p = (acc0 + acc1) + (acc2 + acc3);

        if (half) pbuf[j] = p;          // wave-uniform branch (waves 2,3)
        __syncthreads();

        if (!half) {                    // waves 0,1 finish output j
            const float a = fmaf(xs[t], wih_j, bias_j) + p + pbuf[j];
            // tanh(a) = 1 - 2/(exp(2a)+1); saturation correct at +-inf
            const float e = __expf(2.0f * a);
            const float hnew = 1.0f - __fdividef(2.0f, e + 1.0f);
            hbuf[t & 1][j] = hnew;
            hA = hnew;
        }
        __syncthreads();

        hsrc = hbuf[t & 1][(half << 6) | lane];   // refresh broadcast source
    }
#undef DOT4
#undef RL

    // --- y[b] = sum_j W_out[j] * h_last[j] + b_out  (h in half-0 threads)
    float v = half ? 0.0f : hA * W_out[j];
    #pragma unroll
    for (int off = 32; off >= 1; off >>= 1)
        v += __shfl_xor(v, off, 64);
    if (lane == 0) red[wid] = v;
    __syncthreads();
    if (tid == 0) y[blockIdx.x] = (red[0] + red[1]) + (red[2] + red[3]) + b_out[0];
}

extern "C" void kernel_launch(void* const* d_in, const int* in_sizes, int n_in,
                              void* d_out, int out_size, void* d_ws, size_t ws_size,
                              hipStream_t stream)
{
    const float* x     = (const float*)d_in[0];
    const float* W_ih  = (const float*)d_in[1];
    const float* W_hh  = (const float*)d_in[2];
    const float* b_ih  = (const float*)d_in[3];
    const float* b_hh  = (const float*)d_in[4];
    const float* W_out = (const float*)d_in[5];
    const float* b_out = (const float*)d_in[6];
    float* y = (float*)d_out;

    const int B = in_sizes[0] / T_STEPS;   // x has B*T*1 elements
    rnn_scan_kernel<<<B, 256, 0, stream>>>(x, W_ih, W_hh, b_ih, b_hh,
                                           W_out, b_out, y);
}

// Round 7
// 370.798 us; speedup vs baseline: 1.6836x; 1.6836x over previous
//
#include <hip/hip_runtime.h>

#define T_STEPS 512
#define HID 128
#define ROWS 16   // batch rows per block -> 64 blocks

typedef short bf16x8 __attribute__((ext_vector_type(8)));   // MFMA A/B frag (8 bf16)
typedef float f32x4  __attribute__((ext_vector_type(4)));   // MFMA C/D frag
typedef unsigned int u32;
typedef u32 u32x4 __attribute__((ext_vector_type(4)));

// LDS layout (bytes):
//   0     : h buf0 hi  [16 r][128 j] bf16 (4 KB)   (XOR-swizzled: byte ^= (r&7)<<4)
//   4096  : h buf0 lo
//   8192  : h buf1 hi
//   12288 : h buf1 lo
//   16384 : xs [512 t][16 r] f32 (32 KB)
//   49152 : red [4][16] f32
#define LDS_BYTES (49152 + 256)

__device__ __forceinline__ u32 cvt_pk_bf16(float s0, float s1) {
    u32 d;  // d.lo = bf16(s0), d.hi = bf16(s1)
    asm("v_cvt_pk_bf16_f32 %0, %1, %2" : "=v"(d) : "v"(s0), "v"(s1));
    return d;
}
__device__ __forceinline__ bf16x8 frag_from(u32 a, u32 b, u32 c, u32 d) {
    u32x4 t = {a, b, c, d};
    return __builtin_bit_cast(bf16x8, t);
}
__device__ __forceinline__ float tanh_fast(float a) {
    const float e = __expf(2.0f * a);
    return 1.0f - __fdividef(2.0f, e + 1.0f);  // saturates correctly at +-inf
}

// split 8 f32 into hi/lo bf16 frags (3-term split-bf16 precision)
#define SPLIT8(HI, LO, f0,f1,f2,f3,f4,f5,f6,f7) do {                          \
    u32 h0_ = cvt_pk_bf16(f0,f1), h1_ = cvt_pk_bf16(f2,f3);                   \
    u32 h2_ = cvt_pk_bf16(f4,f5), h3_ = cvt_pk_bf16(f6,f7);                   \
    float l0_ = (f0) - __uint_as_float(h0_ << 16);                            \
    float l1_ = (f1) - __uint_as_float(h0_ & 0xffff0000u);                    \
    float l2_ = (f2) - __uint_as_float(h1_ << 16);                            \
    float l3_ = (f3) - __uint_as_float(h1_ & 0xffff0000u);                    \
    float l4_ = (f4) - __uint_as_float(h2_ << 16);                            \
    float l5_ = (f5) - __uint_as_float(h2_ & 0xffff0000u);                    \
    float l6_ = (f6) - __uint_as_float(h3_ << 16);                            \
    float l7_ = (f7) - __uint_as_float(h3_ & 0xffff0000u);                    \
    u32 g0_ = cvt_pk_bf16(l0_,l1_), g1_ = cvt_pk_bf16(l2_,l3_);               \
    u32 g2_ = cvt_pk_bf16(l4_,l5_), g3_ = cvt_pk_bf16(l6_,l7_);               \
    HI = frag_from(h0_,h1_,h2_,h3_); LO = frag_from(g0_,g1_,g2_,g3_);         \
} while (0)

#define MFMA3(ACC, WH, WL, BH, BL)                                            \
    ACC = __builtin_amdgcn_mfma_f32_16x16x32_bf16(WH, BH, ACC, 0,0,0);        \
    ACC = __builtin_amdgcn_mfma_f32_16x16x32_bf16(WH, BL, ACC, 0,0,0);        \
    ACC = __builtin_amdgcn_mfma_f32_16x16x32_bf16(WL, BH, ACC, 0,0,0);

__global__ __launch_bounds__(256, 1)
__attribute__((amdgpu_waves_per_eu(1, 1)))
void rnn_mfma_kernel(const float* __restrict__ x,
                     const float* __restrict__ W_ih,
                     const float* __restrict__ W_hh,
                     const float* __restrict__ b_ih,
                     const float* __restrict__ b_hh,
                     const float* __restrict__ W_out,
                     const float* __restrict__ b_out,
                     float* __restrict__ y)
{
    __shared__ __align__(16) char lds[LDS_BYTES];

    const int tid = threadIdx.x;
    const int w   = tid >> 6;          // wave 0..3: owns j in [32w, 32w+32)
    const int l   = tid & 63;
    const int r   = l & 15;            // batch row (N index / B-frag col / C col)
    const int q   = l >> 4;            // lane quarter (k-group / C row group)
    const int b0  = blockIdx.x * ROWS;

    // ---- stage x -> xs[t][r] (transposed; coalesced reads) + zero h buf0
    for (int i = tid; i < ROWS * T_STEPS; i += 256) {
        const int rr = i >> 9, tt = i & 511;
        *(float*)&lds[16384 + (tt * 16 + rr) * 4] = x[(size_t)(b0 + rr) * T_STEPS + tt];
    }
    {
        const u32x4 z = {0,0,0,0};
        *(u32x4*)&lds[tid * 16]        = z;   // buf0 hi
        *(u32x4*)&lds[4096 + tid * 16] = z;   // buf0 lo
    }

    // ---- W_hh A-fragments (static; 16 named frags). A[m=j][k]; j = 32w+16tt+r... m = l&15
    bf16x8 Whi00,Whi01,Whi02,Whi03, Whi10,Whi11,Whi12,Whi13;
    bf16x8 Wlo00,Wlo01,Wlo02,Wlo03, Wlo10,Wlo11,Wlo12,Wlo13;
#define LOADW(HI, LO, TT, C) do {                                             \
    const float* p_ = W_hh + (size_t)(32*w + 16*(TT) + r) * HID + q*8 + (C)*32;\
    float4 fa_ = *(const float4*)p_;                                          \
    float4 fb_ = *(const float4*)(p_ + 4);                                    \
    SPLIT8(HI, LO, fa_.x,fa_.y,fa_.z,fa_.w, fb_.x,fb_.y,fb_.z,fb_.w);         \
} while (0)
    LOADW(Whi00,Wlo00,0,0); LOADW(Whi01,Wlo01,0,1);
    LOADW(Whi02,Wlo02,0,2); LOADW(Whi03,Wlo03,0,3);
    LOADW(Whi10,Wlo10,1,0); LOADW(Whi11,Wlo11,1,1);
    LOADW(Whi12,Wlo12,1,2); LOADW(Whi13,Wlo13,1,3);

    // ---- per-lane epilogue/init constants: this lane's 8 output j's
    const int j0 = 32 * w + 4 * q;          // tile0 rows 4q..4q+3 ; tile1 = +16
    const float4 wih0  = *(const float4*)(W_ih + j0);
    const float4 wih1  = *(const float4*)(W_ih + j0 + 16);
    float4 bias0, bias1;
    {
        const float4 bi0 = *(const float4*)(b_ih + j0);
        const float4 bh0 = *(const float4*)(b_hh + j0);
        const float4 bi1 = *(const float4*)(b_ih + j0 + 16);
        const float4 bh1 = *(const float4*)(b_hh + j0 + 16);
        bias0.x = bi0.x + bh0.x; bias0.y = bi0.y + bh0.y;
        bias0.z = bi0.z + bh0.z; bias0.w = bi0.w + bh0.w;
        bias1.x = bi1.x + bh1.x; bias1.y = bi1.y + bh1.y;
        bias1.z = bi1.z + bh1.z; bias1.w = bi1.w + bh1.w;
    }

    // ---- precomputed swizzled LDS offsets
    const int swz   = (r & 7) << 4;
    const int voff0 = (r*256 + q*16 +   0) ^ swz;   // B-frag read, k-chunk c: +64c before XOR
    const int voff1 = (r*256 + q*16 +  64) ^ swz;
    const int voff2 = (r*256 + q*16 + 128) ^ swz;
    const int voff3 = (r*256 + q*16 + 192) ^ swz;
    const int woff0 = (r*256 + w*64 +      q*8) ^ swz;  // h write, tile0 (8B)
    const int woff1 = (r*256 + w*64 + 32 + q*8) ^ swz;  // tile1

    __syncthreads();

    u32 xaddr = 16384u + (u32)r * 4u;
    f32x4 hv0, hv1;  // last-step h values (this lane's 8 j's)

#define STEP(RB, WB) do {                                                     \
    const float xt = *(const float*)&lds[xaddr]; xaddr += 64;                 \
    bf16x8 Bh0 = *(const bf16x8*)&lds[(RB) + voff0];                          \
    bf16x8 Bh1 = *(const bf16x8*)&lds[(RB) + voff1];                          \
    bf16x8 Bh2 = *(const bf16x8*)&lds[(RB) + voff2];                          \
    bf16x8 Bh3 = *(const bf16x8*)&lds[(RB) + voff3];                          \
    bf16x8 Bl0 = *(const bf16x8*)&lds[(RB) + 4096 + voff0];                   \
    bf16x8 Bl1 = *(const bf16x8*)&lds[(RB) + 4096 + voff1];                   \
    bf16x8 Bl2 = *(const bf16x8*)&lds[(RB) + 4096 + voff2];                   \
    bf16x8 Bl3 = *(const bf16x8*)&lds[(RB) + 4096 + voff3];                   \
    f32x4 acc0, acc1;                                                         \
    acc0[0]=fmaf(xt,wih0.x,bias0.x); acc0[1]=fmaf(xt,wih0.y,bias0.y);         \
    acc0[2]=fmaf(xt,wih0.z,bias0.z); acc0[3]=fmaf(xt,wih0.w,bias0.w);         \
    acc1[0]=fmaf(xt,wih1.x,bias1.x); acc1[1]=fmaf(xt,wih1.y,bias1.y);         \
    acc1[2]=fmaf(xt,wih1.z,bias1.z); acc1[3]=fmaf(xt,wih1.w,bias1.w);         \
    MFMA3(acc0, Whi00, Wlo00, Bh0, Bl0)                                       \
    MFMA3(acc1, Whi10, Wlo10, Bh0, Bl0)                                       \
    MFMA3(acc0, Whi01, Wlo01, Bh1, Bl1)                                       \
    MFMA3(acc1, Whi11, Wlo11, Bh1, Bl1)                                       \
    MFMA3(acc0, Whi02, Wlo02, Bh2, Bl2)                                       \
    MFMA3(acc1, Whi12, Wlo12, Bh2, Bl2)                                       \
    MFMA3(acc0, Whi03, Wlo03, Bh3, Bl3)                                       \
    MFMA3(acc1, Whi13, Wlo13, Bh3, Bl3)                                       \
    hv0[0]=tanh_fast(acc0[0]); hv0[1]=tanh_fast(acc0[1]);                     \
    hv0[2]=tanh_fast(acc0[2]); hv0[3]=tanh_fast(acc0[3]);                     \
    hv1[0]=tanh_fast(acc1[0]); hv1[1]=tanh_fast(acc1[1]);                     \
    hv1[2]=tanh_fast(acc1[2]); hv1[3]=tanh_fast(acc1[3]);                     \
    {                                                                         \
        u32 a0 = cvt_pk_bf16(hv0[0], hv0[1]), a1 = cvt_pk_bf16(hv0[2], hv0[3]);\
        float m0 = hv0[0] - __uint_as_float(a0 << 16);                        \
        float m1 = hv0[1] - __uint_as_float(a0 & 0xffff0000u);                \
        float m2 = hv0[2] - __uint_as_float(a1 << 16);                        \
        float m3 = hv0[3] - __uint_as_float(a1 & 0xffff0000u);                \
        u32 c0 = cvt_pk_bf16(m0, m1), c1 = cvt_pk_bf16(m2, m3);               \
        *(uint2*)&lds[(WB) + woff0]        = make_uint2(a0, a1);              \
        *(uint2*)&lds[(WB) + 4096 + woff0] = make_uint2(c0, c1);              \
    }                                                                         \
    {                                                                         \
        u32 a0 = cvt_pk_bf16(hv1[0], hv1[1]), a1 = cvt_pk_bf16(hv1[2], hv1[3]);\
        float m0 = hv1[0] - __uint_as_float(a0 << 16);                        \
        float m1 = hv1[1] - __uint_as_float(a0 & 0xffff0000u);                \
        float m2 = hv1[2] - __uint_as_float(a1 << 16);                        \
        float m3 = hv1[3] - __uint_as_float(a1 & 0xffff0000u);                \
        u32 c0 = cvt_pk_bf16(m0, m1), c1 = cvt_pk_bf16(m2, m3);               \
        *(uint2*)&lds[(WB) + woff1]        = make_uint2(a0, a1);              \
        *(uint2*)&lds[(WB) + 4096 + woff1] = make_uint2(c0, c1);              \
    }                                                                         \
    __syncthreads();                                                          \
} while (0)

    for (int it = 0; it < T_STEPS; it += 2) {
        STEP(0, 8192);      // read h from buf0, write buf1
        STEP(8192, 0);      // read buf1, write buf0
    }

    // ---- y[b0+r] = sum_j W_out[j] * h_last[j] + b_out
    const float4 wo0 = *(const float4*)(W_out + j0);
    const float4 wo1 = *(const float4*)(W_out + j0 + 16);
    float v = wo0.x*hv0[0] + wo0.y*hv0[1] + wo0.z*hv0[2] + wo0.w*hv0[3]
            + wo1.x*hv1[0] + wo1.y*hv1[1] + wo1.z*hv1[2] + wo1.w*hv1[3];
    v += __shfl_xor(v, 16, 64);
    v += __shfl_xor(v, 32, 64);     // all 4 quarters of col r summed
    if (q == 0) *(float*)&lds[49152 + (w * 16 + r) * 4] = v;
    __syncthreads();
    if (tid < 16) {
        const float s = *(const float*)&lds[49152 + tid * 4]
                      + *(const float*)&lds[49152 + 64  + tid * 4]
                      + *(const float*)&lds[49152 + 128 + tid * 4]
                      + *(const float*)&lds[49152 + 192 + tid * 4];
        y[b0 + tid] = s + b_out[0];
    }
}

extern "C" void kernel_launch(void* const* d_in, const int* in_sizes, int n_in,
                              void* d_out, int out_size, void* d_ws, size_t ws_size,
                              hipStream_t stream)
{
    const float* x     = (const float*)d_in[0];
    const float* W_ih  = (const float*)d_in[1];
    const float* W_hh  = (const float*)d_in[2];
    const float* b_ih  = (const float*)d_in[3];
    const float* b_hh  = (const float*)d_in[4];
    const float* W_out = (const float*)d_in[5];
    const float* b_out = (const float*)d_in[6];
    float* y = (float*)d_out;

    const int B = in_sizes[0] / T_STEPS;   // 1024
    rnn_mfma_kernel<<<B / ROWS, 256, 0, stream>>>(x, W_ih, W_hh, b_ih, b_hh,
                                                  W_out, b_out, y);
}

// Round 8
// 318.954 us; speedup vs baseline: 1.9573x; 1.1625x over previous
//
#include <hip/hip_runtime.h>

#define T_STEPS 512
#define HID 128
#define ROWS 16   // batch rows per block -> 64 blocks

typedef short bf16x8 __attribute__((ext_vector_type(8)));   // MFMA A/B frag (8 bf16)
typedef float f32x4  __attribute__((ext_vector_type(4)));   // MFMA C/D frag
typedef unsigned int u32;
typedef u32 u32x4 __attribute__((ext_vector_type(4)));

// LDS layout (bytes):
//   0     : h buf0  [16 r][128 j] bf16 (4 KB)  (XOR-swizzled: byte ^= (r&7)<<4)
//   4096  : h buf1
//   8192  : xs [512 t][16 r] f32 (32 KB)
//   40960 : red [4][16] f32
#define LDS_BYTES (40960 + 256)

__device__ __forceinline__ u32 cvt_pk_bf16(float s0, float s1) {
    u32 d;  // d.lo = bf16(s0), d.hi = bf16(s1)
    asm("v_cvt_pk_bf16_f32 %0, %1, %2" : "=v"(d) : "v"(s0), "v"(s1));
    return d;
}
__device__ __forceinline__ bf16x8 frag_from(u32 a, u32 b, u32 c, u32 d) {
    u32x4 t = {a, b, c, d};
    return __builtin_bit_cast(bf16x8, t);
}
__device__ __forceinline__ float tanh_fast(float a) {
    const float e = __expf(2.0f * a);
    return 1.0f - __fdividef(2.0f, e + 1.0f);  // saturates correctly at +-inf
}

// split 8 f32 into hi/lo bf16 frags (W kept to ~2^-18 rel as Whi+Wlo)
#define SPLIT8(HI, LO, f0,f1,f2,f3,f4,f5,f6,f7) do {                          \
    u32 h0_ = cvt_pk_bf16(f0,f1), h1_ = cvt_pk_bf16(f2,f3);                   \
    u32 h2_ = cvt_pk_bf16(f4,f5), h3_ = cvt_pk_bf16(f6,f7);                   \
    float l0_ = (f0) - __uint_as_float(h0_ << 16);                            \
    float l1_ = (f1) - __uint_as_float(h0_ & 0xffff0000u);                    \
    float l2_ = (f2) - __uint_as_float(h1_ << 16);                            \
    float l3_ = (f3) - __uint_as_float(h1_ & 0xffff0000u);                    \
    float l4_ = (f4) - __uint_as_float(h2_ << 16);                            \
    float l5_ = (f5) - __uint_as_float(h2_ & 0xffff0000u);                    \
    float l6_ = (f6) - __uint_as_float(h3_ << 16);                            \
    float l7_ = (f7) - __uint_as_float(h3_ & 0xffff0000u);                    \
    u32 g0_ = cvt_pk_bf16(l0_,l1_), g1_ = cvt_pk_bf16(l2_,l3_);               \
    u32 g2_ = cvt_pk_bf16(l4_,l5_), g3_ = cvt_pk_bf16(l6_,l7_);               \
    HI = frag_from(h0_,h1_,h2_,h3_); LO = frag_from(g0_,g1_,g2_,g3_);         \
} while (0)

#define MFMA(ACC, A, B) \
    ACC = __builtin_amdgcn_mfma_f32_16x16x32_bf16(A, B, ACC, 0, 0, 0);

__global__ __launch_bounds__(256, 1)
__attribute__((amdgpu_waves_per_eu(1, 1)))
void rnn_mfma_kernel(const float* __restrict__ x,
                     const float* __restrict__ W_ih,
                     const float* __restrict__ W_hh,
                     const float* __restrict__ b_ih,
                     const float* __restrict__ b_hh,
                     const float* __restrict__ W_out,
                     const float* __restrict__ b_out,
                     float* __restrict__ y)
{
    __shared__ __align__(16) char lds[LDS_BYTES];

    const int tid = threadIdx.x;
    const int w   = tid >> 6;          // wave 0..3: owns j in [32w, 32w+32)
    const int l   = tid & 63;
    const int r   = l & 15;            // batch row (B/C col)
    const int q   = l >> 4;            // lane quarter (k-group / C row group)
    const int b0  = blockIdx.x * ROWS;

    // ---- stage x -> xs[t][r] (transposed) + zero h buf0
    for (int i = tid; i < ROWS * T_STEPS; i += 256) {
        const int rr = i >> 9, tt = i & 511;
        *(float*)&lds[8192 + (tt * 16 + rr) * 4] = x[(size_t)(b0 + rr) * T_STEPS + tt];
    }
    {
        const u32x4 z = {0,0,0,0};
        *(u32x4*)&lds[tid * 16] = z;   // buf0
    }

    // ---- W_hh A-fragments (16 named frags: 2 M-tiles x 4 K-chunks x hi/lo)
    bf16x8 Whi00,Whi01,Whi02,Whi03, Whi10,Whi11,Whi12,Whi13;
    bf16x8 Wlo00,Wlo01,Wlo02,Wlo03, Wlo10,Wlo11,Wlo12,Wlo13;
#define LOADW(HI, LO, TT, C) do {                                             \
    const float* p_ = W_hh + (size_t)(32*w + 16*(TT) + r) * HID + q*8 + (C)*32;\
    float4 fa_ = *(const float4*)p_;                                          \
    float4 fb_ = *(const float4*)(p_ + 4);                                    \
    SPLIT8(HI, LO, fa_.x,fa_.y,fa_.z,fa_.w, fb_.x,fb_.y,fb_.z,fb_.w);         \
} while (0)
    LOADW(Whi00,Wlo00,0,0); LOADW(Whi01,Wlo01,0,1);
    LOADW(Whi02,Wlo02,0,2); LOADW(Whi03,Wlo03,0,3);
    LOADW(Whi10,Wlo10,1,0); LOADW(Whi11,Wlo11,1,1);
    LOADW(Whi12,Wlo12,1,2); LOADW(Whi13,Wlo13,1,3);

    // ---- per-lane constants: this lane's 8 output j's
    const int j0 = 32 * w + 4 * q;          // tile0 rows 4q..4q+3 ; tile1 = +16
    const float4 wih0  = *(const float4*)(W_ih + j0);
    const float4 wih1  = *(const float4*)(W_ih + j0 + 16);
    float4 bias0, bias1;
    {
        const float4 bi0 = *(const float4*)(b_ih + j0);
        const float4 bh0 = *(const float4*)(b_hh + j0);
        const float4 bi1 = *(const float4*)(b_ih + j0 + 16);
        const float4 bh1 = *(const float4*)(b_hh + j0 + 16);
        bias0.x = bi0.x + bh0.x; bias0.y = bi0.y + bh0.y;
        bias0.z = bi0.z + bh0.z; bias0.w = bi0.w + bh0.w;
        bias1.x = bi1.x + bh1.x; bias1.y = bi1.y + bh1.y;
        bias1.z = bi1.z + bh1.z; bias1.w = bi1.w + bh1.w;
    }

    // ---- precomputed swizzled LDS offsets (single bf16 plane now)
    const int swz   = (r & 7) << 4;
    const int voff0 = (r*256 + q*16 +   0) ^ swz;   // B-frag read, k-chunk c
    const int voff1 = (r*256 + q*16 +  64) ^ swz;
    const int voff2 = (r*256 + q*16 + 128) ^ swz;
    const int voff3 = (r*256 + q*16 + 192) ^ swz;
    const int woff0 = (r*256 + w*64 +      q*8) ^ swz;  // h write, tile0 (8B)
    const int woff1 = (r*256 + w*64 + 32 + q*8) ^ swz;  // tile1

    __syncthreads();

    u32 xaddr = 8192u + 64u + (u32)r * 4u;          // points at x[t+1]
    float xt = *(const float*)&lds[8192 + r * 4];   // x[0]
    f32x4 hv0, hv1;  // last-step h values (this lane's 8 j's)

#define STEP(RB, WB) do {                                                     \
    bf16x8 B0 = *(const bf16x8*)&lds[(RB) + voff0];                           \
    bf16x8 B1 = *(const bf16x8*)&lds[(RB) + voff1];                           \
    bf16x8 B2 = *(const bf16x8*)&lds[(RB) + voff2];                           \
    bf16x8 B3 = *(const bf16x8*)&lds[(RB) + voff3];                           \
    f32x4 a00, a01, a02, a03, a10, a11, a12, a13;                             \
    a00[0]=fmaf(xt,wih0.x,bias0.x); a00[1]=fmaf(xt,wih0.y,bias0.y);           \
    a00[2]=fmaf(xt,wih0.z,bias0.z); a00[3]=fmaf(xt,wih0.w,bias0.w);           \
    a10[0]=fmaf(xt,wih1.x,bias1.x); a10[1]=fmaf(xt,wih1.y,bias1.y);           \
    a10[2]=fmaf(xt,wih1.z,bias1.z); a10[3]=fmaf(xt,wih1.w,bias1.w);           \
    a01 = (f32x4)(0.0f); a02 = (f32x4)(0.0f); a03 = (f32x4)(0.0f);            \
    a11 = (f32x4)(0.0f); a12 = (f32x4)(0.0f); a13 = (f32x4)(0.0f);            \
    const float xt_n = *(const float*)&lds[xaddr];                            \
    /* 16 MFMAs: independent (tile,chunk) accs; dep chain = 2 */              \
    MFMA(a00, Whi00, B0) MFMA(a10, Whi10, B0)                                 \
    MFMA(a01, Whi01, B1) MFMA(a11, Whi11, B1)                                 \
    MFMA(a00, Wlo00, B0) MFMA(a10, Wlo10, B0)                                 \
    MFMA(a01, Wlo01, B1) MFMA(a11, Wlo11, B1)                                 \
    MFMA(a02, Whi02, B2) MFMA(a12, Whi12, B2)                                 \
    MFMA(a03, Whi03, B3) MFMA(a13, Whi13, B3)                                 \
    MFMA(a02, Wlo02, B2) MFMA(a12, Wlo12, B2)                                 \
    MFMA(a03, Wlo03, B3) MFMA(a13, Wlo13, B3)                                 \
    const f32x4 s0 = (a00 + a01) + (a02 + a03);                               \
    const f32x4 s1 = (a10 + a11) + (a12 + a13);                               \
    hv0[0]=tanh_fast(s0[0]); hv0[1]=tanh_fast(s0[1]);                         \
    hv0[2]=tanh_fast(s0[2]); hv0[3]=tanh_fast(s0[3]);                         \
    hv1[0]=tanh_fast(s1[0]); hv1[1]=tanh_fast(s1[1]);                         \
    hv1[2]=tanh_fast(s1[2]); hv1[3]=tanh_fast(s1[3]);                         \
    *(uint2*)&lds[(WB) + woff0] =                                             \
        make_uint2(cvt_pk_bf16(hv0[0],hv0[1]), cvt_pk_bf16(hv0[2],hv0[3]));   \
    *(uint2*)&lds[(WB) + woff1] =                                             \
        make_uint2(cvt_pk_bf16(hv1[0],hv1[1]), cvt_pk_bf16(hv1[2],hv1[3]));   \
    xt = xt_n; xaddr += 64;                                                   \
    __syncthreads();                                                          \
} while (0)

    for (int it = 0; it < T_STEPS; it += 2) {
        STEP(0, 4096);      // read h from buf0, write buf1
        STEP(4096, 0);      // read buf1, write buf0
    }
#undef STEP

    // ---- y[b0+r] = sum_j W_out[j] * h_last[j] + b_out
    const float4 wo0 = *(const float4*)(W_out + j0);
    const float4 wo1 = *(const float4*)(W_out + j0 + 16);
    float v = wo0.x*hv0[0] + wo0.y*hv0[1] + wo0.z*hv0[2] + wo0.w*hv0[3]
            + wo1.x*hv1[0] + wo1.y*hv1[1] + wo1.z*hv1[2] + wo1.w*hv1[3];
    v += __shfl_xor(v, 16, 64);
    v += __shfl_xor(v, 32, 64);     // all 4 quarters of col r summed
    if (q == 0) *(float*)&lds[40960 + (w * 16 + r) * 4] = v;
    __syncthreads();
    if (tid < 16) {
        const float s = *(const float*)&lds[40960 + tid * 4]
                      + *(const float*)&lds[40960 + 64  + tid * 4]
                      + *(const float*)&lds[40960 + 128 + tid * 4]
                      + *(const float*)&lds[40960 + 192 + tid * 4];
        y[b0 + tid] = s + b_out[0];
    }
}

extern "C" void kernel_launch(void* const* d_in, const int* in_sizes, int n_in,
                              void* d_out, int out_size, void* d_ws, size_t ws_size,
                              hipStream_t stream)
{
    const float* x     = (const float*)d_in[0];
    const float* W_ih  = (const float*)d_in[1];
    const float* W_hh  = (const float*)d_in[2];
    const float* b_ih  = (const float*)d_in[3];
    const float* b_hh  = (const float*)d_in[4];
    const float* W_out = (const float*)d_in[5];
    const float* b_out = (const float*)d_in[6];
    float* y = (float*)d_out;

    const int B = in_sizes[0] / T_STEPS;   // 1024
    rnn_mfma_kernel<<<B / ROWS, 256, 0, stream>>>(x, W_ih, W_hh, b_ih, b_hh,
                                                  W_out, b_out, y);
}